// Round 1
// baseline (454.585 us; speedup 1.0000x reference)
//
#include <hip/hip_runtime.h>
#include <stdint.h>

// ---------------------------------------------------------------------------
// Transformer block: LN1 -> QKV GEMM -> flash-MFMA attention -> proj(+res)
//                    -> LN2 -> MLP1(GELU) -> MLP2(+res)
// All matmuls: bf16 inputs, fp32 MFMA accumulation (16x16x32_bf16).
// Verified layouts (learn_hip m89/m91/m120):
//   A-frag:  A[m = lane&15][k = (lane>>4)*8 + j]   (8 bf16, contiguous in k)
//   B-frag:  B[k = (lane>>4)*8 + j][n = lane&15]   (= Bt[n][k], contiguous k)
//   C/D   :  D[m = (lane>>4)*4 + r][n = lane&15]
// ---------------------------------------------------------------------------

#define DIMC 1024
#define HIDN 4096
#define SEQ  2048
#define TOK  4096   // B*N = 2*2048

typedef __bf16 bf16x8 __attribute__((ext_vector_type(8)));
typedef float  f32x4  __attribute__((ext_vector_type(4)));
typedef unsigned short ushort8 __attribute__((ext_vector_type(8)));

__device__ inline unsigned short f2bf(float f) {
  union { float f; unsigned u; } v; v.f = f;
  unsigned u = v.u;
  return (unsigned short)((u + 0x7fffu + ((u >> 16) & 1u)) >> 16);  // RNE
}

__device__ inline f32x4 mfma_bf16(bf16x8 a, bf16x8 b, f32x4 c) {
  return __builtin_amdgcn_mfma_f32_16x16x32_bf16(a, b, c, 0, 0, 0);
}

// ---------------------------------------------------------------------------
// Weight transpose + cast: w[K][N] fp32 -> wt[N][K] bf16
// ---------------------------------------------------------------------------
__global__ __launch_bounds__(256)
void transpose_cast(const float* __restrict__ w, unsigned short* __restrict__ wt,
                    int K, int N) {
  __shared__ float tile[32][33];
  const int k0 = blockIdx.y * 32;
  const int n0 = blockIdx.x * 32;
  const int tx = threadIdx.x & 31;
  const int ty = threadIdx.x >> 5;  // 0..7
#pragma unroll
  for (int i = 0; i < 4; i++)
    tile[ty + i * 8][tx] = w[(size_t)(k0 + ty + i * 8) * N + n0 + tx];
  __syncthreads();
#pragma unroll
  for (int i = 0; i < 4; i++)
    wt[(size_t)(n0 + ty + i * 8) * K + k0 + tx] = f2bf(tile[tx][ty + i * 8]);
}

// ---------------------------------------------------------------------------
// LayerNorm: x[rows][1024] fp32 -> out bf16, per-row mean/var, * g + b
// ---------------------------------------------------------------------------
__global__ __launch_bounds__(256)
void ln_kernel(const float* __restrict__ x, const float* __restrict__ g,
               const float* __restrict__ b, unsigned short* __restrict__ out) {
  const int row = blockIdx.x;
  const int tid = threadIdx.x;
  const float4* xr = (const float4*)&x[(size_t)row * DIMC];
  float4 v = xr[tid];
  float s  = v.x + v.y + v.z + v.w;
  float sq = v.x * v.x + v.y * v.y + v.z * v.z + v.w * v.w;
#pragma unroll
  for (int off = 32; off > 0; off >>= 1) {
    s  += __shfl_xor(s, off, 64);
    sq += __shfl_xor(sq, off, 64);
  }
  __shared__ float red[8];
  if ((tid & 63) == 0) { red[tid >> 6] = s; red[4 + (tid >> 6)] = sq; }
  __syncthreads();
  s  = red[0] + red[1] + red[2] + red[3];
  sq = red[4] + red[5] + red[6] + red[7];
  const float mu  = s * (1.0f / DIMC);
  const float var = sq * (1.0f / DIMC) - mu * mu;
  const float rs  = rsqrtf(var + 1e-5f);
  const int c = tid * 4;
  float vv[4] = {v.x, v.y, v.z, v.w};
#pragma unroll
  for (int j = 0; j < 4; j++)
    out[(size_t)row * DIMC + c + j] = f2bf((vv[j] - mu) * rs * g[c + j] + b[c + j]);
}

// ---------------------------------------------------------------------------
// GEMM: C[M][N] = A[M][K] @ B, with B given transposed Bt[N][K] (bf16).
// 128x128 tile, BK=32, 256 thr = 4 waves (2x2 of 64x64), 4x4 MFMA acc/wave.
// EPI: 0 = store bf16; 1 = +bias[col]+res[idx], store fp32; 2 = gelu(+bias), bf16
// LDS tiles unpadded [128][32] (bank-balanced for b128; global_load_lds-ready).
// ---------------------------------------------------------------------------
template <int EPI>
__global__ __launch_bounds__(256, 2)
void gemm_bt(const unsigned short* __restrict__ A,
             const unsigned short* __restrict__ Bt,
             float* __restrict__ Cf, unsigned short* __restrict__ Cb,
             const float* __restrict__ bias, const float* __restrict__ res,
             int M, int N, int K) {
  __shared__ unsigned short As[128 * 32];
  __shared__ unsigned short Bs[128 * 32];
  const int tid  = threadIdx.x;
  const int lane = tid & 63;
  const int wave = tid >> 6;
  const int m0 = blockIdx.y * 128;
  const int n0 = blockIdx.x * 128;
  const int wm = (wave >> 1) * 64;
  const int wn = (wave & 1) * 64;
  const int lm = lane & 15;
  const int lg = lane >> 4;
  const int arow = tid >> 2;   // 0..63
  const int achk = tid & 3;    // 0..3 -> k-chunk of 8

  f32x4 acc[4][4];
#pragma unroll
  for (int t = 0; t < 4; t++)
#pragma unroll
    for (int u = 0; u < 4; u++) acc[t][u] = {0.f, 0.f, 0.f, 0.f};

  for (int k0 = 0; k0 < K; k0 += 32) {
    ushort8 a0 = *(const ushort8*)&A [(size_t)(m0 + arow)      * K + k0 + achk * 8];
    ushort8 a1 = *(const ushort8*)&A [(size_t)(m0 + 64 + arow) * K + k0 + achk * 8];
    ushort8 b0 = *(const ushort8*)&Bt[(size_t)(n0 + arow)      * K + k0 + achk * 8];
    ushort8 b1 = *(const ushort8*)&Bt[(size_t)(n0 + 64 + arow) * K + k0 + achk * 8];
    __syncthreads();
    *(ushort8*)&As[arow * 32 + achk * 8]        = a0;
    *(ushort8*)&As[(64 + arow) * 32 + achk * 8] = a1;
    *(ushort8*)&Bs[arow * 32 + achk * 8]        = b0;
    *(ushort8*)&Bs[(64 + arow) * 32 + achk * 8] = b1;
    __syncthreads();
    bf16x8 af[4], bfr[4];
#pragma unroll
    for (int t = 0; t < 4; t++) af[t]  = *(const bf16x8*)&As[(wm + t * 16 + lm) * 32 + lg * 8];
#pragma unroll
    for (int u = 0; u < 4; u++) bfr[u] = *(const bf16x8*)&Bs[(wn + u * 16 + lm) * 32 + lg * 8];
#pragma unroll
    for (int t = 0; t < 4; t++)
#pragma unroll
      for (int u = 0; u < 4; u++)
        acc[t][u] = mfma_bf16(af[t], bfr[u], acc[t][u]);
  }

#pragma unroll
  for (int t = 0; t < 4; t++) {
    const int row = m0 + wm + t * 16 + lg * 4;
#pragma unroll
    for (int u = 0; u < 4; u++) {
      const int col = n0 + wn + u * 16 + lm;
#pragma unroll
      for (int r = 0; r < 4; r++) {
        float v = acc[t][u][r];
        size_t idx = (size_t)(row + r) * N + col;
        if (EPI == 0) {
          Cb[idx] = f2bf(v);
        } else if (EPI == 1) {
          Cf[idx] = v + bias[col] + res[idx];
        } else {
          float xg = v + bias[col];
          Cb[idx] = f2bf(0.5f * xg * (1.0f + erff(xg * 0.70710678118654752f)));
        }
      }
    }
  }
}

// ---------------------------------------------------------------------------
// Flash attention (MFMA). qkv[TOK][3072] bf16 (q/k/v interleaved at +0/+1024/
// +2048, head h at h*64). One block = (b,h, 64 q-rows); wave = 16 q-rows.
// K-tile 64 keys in LDS [64][72]; V staged transposed Vt[d][key] [64][72];
// P routed C-layout -> LDS [16][72] -> A-layout (m120 pattern).
// ---------------------------------------------------------------------------
__global__ __launch_bounds__(256, 2)
void attn_kernel(const unsigned short* __restrict__ qkv,
                 unsigned short* __restrict__ out) {
  const int qt = blockIdx.x;       // q-tile (64 rows)
  const int bh = blockIdx.y;
  const int b  = bh >> 4;
  const int h  = bh & 15;
  const int tid  = threadIdx.x;
  const int lane = tid & 63;
  const int wave = tid >> 6;
  const int lm = lane & 15;
  const int lg = lane >> 4;

  __shared__ unsigned short Ks[64 * 72];
  __shared__ unsigned short Vt[64 * 72];
  __shared__ unsigned short Ps[4][16 * 72];

  const int qrow_base = b * SEQ + qt * 64 + wave * 16;
  bf16x8 qa[2];
#pragma unroll
  for (int c = 0; c < 2; c++)
    qa[c] = *(const bf16x8*)&qkv[(size_t)(qrow_base + lm) * 3072 + h * 64 + c * 32 + lg * 8];

  f32x4 o[4];
#pragma unroll
  for (int dt = 0; dt < 4; dt++) o[dt] = {0.f, 0.f, 0.f, 0.f};
  float mi[4], li[4];
#pragma unroll
  for (int r = 0; r < 4; r++) { mi[r] = -1e30f; li[r] = 0.f; }

  const int key_l = tid & 63;   // staging: lane-consecutive keys (bank-free writes)
  const int chk_l = tid >> 6;   // 0..3 (d-chunks of 8; +4 for second half)

  for (int kt = 0; kt < SEQ / 64; kt++) {
    const size_t krow = (size_t)(b * SEQ + kt * 64 + key_l) * 3072;
    ushort8 kv0 = *(const ushort8*)&qkv[krow + 1024 + h * 64 + chk_l * 8];
    ushort8 kv1 = *(const ushort8*)&qkv[krow + 1024 + h * 64 + (chk_l + 4) * 8];
    ushort8 vv0 = *(const ushort8*)&qkv[krow + 2048 + h * 64 + chk_l * 8];
    ushort8 vv1 = *(const ushort8*)&qkv[krow + 2048 + h * 64 + (chk_l + 4) * 8];
    __syncthreads();
    *(ushort8*)&Ks[key_l * 72 + chk_l * 8]       = kv0;
    *(ushort8*)&Ks[key_l * 72 + (chk_l + 4) * 8] = kv1;
#pragma unroll
    for (int j = 0; j < 8; j++) {
      Vt[(chk_l * 8 + j) * 72 + key_l]       = vv0[j];
      Vt[((chk_l + 4) * 8 + j) * 72 + key_l] = vv1[j];
    }
    __syncthreads();

    // S = (Q @ K^T) * 0.125
    f32x4 s[4];
#pragma unroll
    for (int u = 0; u < 4; u++) {
      bf16x8 kb0 = *(const bf16x8*)&Ks[(u * 16 + lm) * 72 + lg * 8];
      bf16x8 kb1 = *(const bf16x8*)&Ks[(u * 16 + lm) * 72 + 32 + lg * 8];
      f32x4 z = {0.f, 0.f, 0.f, 0.f};
      z = mfma_bf16(qa[0], kb0, z);
      z = mfma_bf16(qa[1], kb1, z);
      s[u] = z;
    }
    float alpha[4];
#pragma unroll
    for (int r = 0; r < 4; r++) {
      float mx = -1e30f;
#pragma unroll
      for (int u = 0; u < 4; u++) { s[u][r] *= 0.125f; mx = fmaxf(mx, s[u][r]); }
      mx = fmaxf(mx, __shfl_xor(mx, 1, 64));
      mx = fmaxf(mx, __shfl_xor(mx, 2, 64));
      mx = fmaxf(mx, __shfl_xor(mx, 4, 64));
      mx = fmaxf(mx, __shfl_xor(mx, 8, 64));
      const float mnew = fmaxf(mi[r], mx);
      alpha[r] = __expf(mi[r] - mnew);
      float ps = 0.f;
#pragma unroll
      for (int u = 0; u < 4; u++) { float p = __expf(s[u][r] - mnew); s[u][r] = p; ps += p; }
      ps += __shfl_xor(ps, 1, 64);
      ps += __shfl_xor(ps, 2, 64);
      ps += __shfl_xor(ps, 4, 64);
      ps += __shfl_xor(ps, 8, 64);
      li[r] = li[r] * alpha[r] + ps;
      mi[r] = mnew;
    }
#pragma unroll
    for (int dt = 0; dt < 4; dt++)
#pragma unroll
      for (int r = 0; r < 4; r++) o[dt][r] *= alpha[r];

    // P: C-layout -> LDS (per-wave buffer; in-wave dep, no barrier needed)
#pragma unroll
    for (int u = 0; u < 4; u++)
#pragma unroll
      for (int r = 0; r < 4; r++)
        Ps[wave][(lg * 4 + r) * 72 + u * 16 + lm] = f2bf(s[u][r]);

    // O += P @ V
#pragma unroll
    for (int kc = 0; kc < 2; kc++) {
      bf16x8 pa = *(const bf16x8*)&Ps[wave][lm * 72 + kc * 32 + lg * 8];
#pragma unroll
      for (int dt = 0; dt < 4; dt++) {
        bf16x8 vb = *(const bf16x8*)&Vt[(dt * 16 + lm) * 72 + kc * 32 + lg * 8];
        o[dt] = mfma_bf16(pa, vb, o[dt]);
      }
    }
  }

#pragma unroll
  for (int dt = 0; dt < 4; dt++)
#pragma unroll
    for (int r = 0; r < 4; r++) {
      float v = o[dt][r] / li[r];
      out[(size_t)(qrow_base + lg * 4 + r) * DIMC + h * 64 + dt * 16 + lm] = f2bf(v);
    }
}

// ---------------------------------------------------------------------------
extern "C" void kernel_launch(void* const* d_in, const int* in_sizes, int n_in,
                              void* d_out, int out_size, void* d_ws, size_t ws_size,
                              hipStream_t stream) {
  const float* x      = (const float*)d_in[0];
  const float* ln1_g  = (const float*)d_in[1];
  const float* ln1_b  = (const float*)d_in[2];
  const float* w_qkv  = (const float*)d_in[3];
  const float* w_proj = (const float*)d_in[4];
  const float* b_proj = (const float*)d_in[5];
  const float* ln2_g  = (const float*)d_in[6];
  const float* ln2_b  = (const float*)d_in[7];
  const float* w1     = (const float*)d_in[8];
  const float* b1     = (const float*)d_in[9];
  const float* w2     = (const float*)d_in[10];
  const float* b2     = (const float*)d_in[11];
  float* out = (float*)d_out;

  char* ws = (char*)d_ws;
  size_t off = 0;
  auto alloc = [&](size_t bytes) { void* p = ws + off; off += (bytes + 255) & ~(size_t)255; return p; };
  unsigned short* wqkvT = (unsigned short*)alloc((size_t)3072 * 1024 * 2);  //  6 MB
  unsigned short* wprjT = (unsigned short*)alloc((size_t)1024 * 1024 * 2);  //  2 MB
  unsigned short* w1T   = (unsigned short*)alloc((size_t)4096 * 1024 * 2);  //  8 MB
  unsigned short* w2T   = (unsigned short*)alloc((size_t)1024 * 4096 * 2);  //  8 MB
  unsigned short* hb    = (unsigned short*)alloc((size_t)TOK * 1024 * 2);   //  8 MB (LN out, reused)
  unsigned short* qkvb  = (unsigned short*)alloc((size_t)TOK * 3072 * 2);   // 24 MB
  unsigned short* attnb = (unsigned short*)alloc((size_t)TOK * 1024 * 2);   //  8 MB
  float*          x1    = (float*)         alloc((size_t)TOK * 1024 * 4);   // 16 MB
  unsigned short* hidb  = (unsigned short*)alloc((size_t)TOK * 4096 * 2);   // 32 MB  (total 112 MB)

  // 1. weight transpose+cast to bf16 [N][K]
  transpose_cast<<<dim3(3072 / 32, 1024 / 32), 256, 0, stream>>>(w_qkv, wqkvT, 1024, 3072);
  transpose_cast<<<dim3(1024 / 32, 1024 / 32), 256, 0, stream>>>(w_proj, wprjT, 1024, 1024);
  transpose_cast<<<dim3(4096 / 32, 1024 / 32), 256, 0, stream>>>(w1, w1T, 1024, 4096);
  transpose_cast<<<dim3(1024 / 32, 4096 / 32), 256, 0, stream>>>(w2, w2T, 4096, 1024);
  // 2. LN1
  ln_kernel<<<TOK, 256, 0, stream>>>(x, ln1_g, ln1_b, hb);
  // 3. QKV = h @ w_qkv  -> bf16
  gemm_bt<0><<<dim3(3072 / 128, TOK / 128), 256, 0, stream>>>(
      hb, wqkvT, nullptr, qkvb, nullptr, nullptr, TOK, 3072, 1024);
  // 4. attention
  attn_kernel<<<dim3(SEQ / 64, 32), 256, 0, stream>>>(qkvb, attnb);
  // 5. x1 = x + attn @ w_proj + b_proj  (fp32)
  gemm_bt<1><<<dim3(1024 / 128, TOK / 128), 256, 0, stream>>>(
      attnb, wprjT, x1, nullptr, b_proj, x, TOK, 1024, 1024);
  // 6. LN2
  ln_kernel<<<TOK, 256, 0, stream>>>(x1, ln2_g, ln2_b, hb);
  // 7. hid = gelu(h @ w1 + b1) -> bf16
  gemm_bt<2><<<dim3(4096 / 128, TOK / 128), 256, 0, stream>>>(
      hb, w1T, nullptr, hidb, b1, nullptr, TOK, 4096, 1024);
  // 8. out = x1 + hid @ w2 + b2  (fp32)
  gemm_bt<1><<<dim3(1024 / 128, TOK / 128), 256, 0, stream>>>(
      hidb, w2T, out, nullptr, b2, x1, TOK, 1024, 4096);
}

// Round 2
// 425.443 us; speedup vs baseline: 1.0685x; 1.0685x over previous
//
#include <hip/hip_runtime.h>
#include <stdint.h>

// ---------------------------------------------------------------------------
// Transformer block: LN1 -> QKV GEMM -> flash-MFMA attention -> proj(+res)
//                    -> LN2 -> MLP1(GELU) -> MLP2(+res)
// All matmuls: bf16 inputs, fp32 MFMA accumulation (16x16x32_bf16).
// Verified layouts (learn_hip m89/m91/m120):
//   A-frag:  A[m = lane&15][k = (lane>>4)*8 + j]   (8 bf16, contiguous in k)
//   B-frag:  B[k = (lane>>4)*8 + j][n = lane&15]   (= Bt[n][k], contiguous k)
//   C/D   :  D[m = (lane>>4)*4 + r][n = lane&15]
// Attention computes S^T = K@Q^T (A=K natural, B=Q natural) so softmax rows
// live per-lane (q = lane&15): in-lane reduce + 2 shuffles over lane>>4.
// ---------------------------------------------------------------------------

#define DIMC 1024
#define HIDN 4096
#define SEQ  2048
#define TOK  4096   // B*N = 2*2048

typedef __bf16 bf16x8 __attribute__((ext_vector_type(8)));
typedef float  f32x4  __attribute__((ext_vector_type(4)));
typedef unsigned short ushort8 __attribute__((ext_vector_type(8)));
typedef unsigned short ushort4v __attribute__((ext_vector_type(4)));

__device__ inline unsigned short f2bf(float f) {
  union { float f; unsigned u; } v; v.f = f;
  unsigned u = v.u;
  return (unsigned short)((u + 0x7fffu + ((u >> 16) & 1u)) >> 16);  // RNE
}

__device__ inline f32x4 mfma_bf16(bf16x8 a, bf16x8 b, f32x4 c) {
  return __builtin_amdgcn_mfma_f32_16x16x32_bf16(a, b, c, 0, 0, 0);
}

// async global->LDS, 16B per lane; LDS dest = wave-uniform base + lane*16
typedef const __attribute__((address_space(1))) unsigned int* as1_u32p;
typedef __attribute__((address_space(3))) unsigned int* as3_u32p;
__device__ inline void gload_lds16(const unsigned short* g, unsigned short* l) {
  __builtin_amdgcn_global_load_lds((as1_u32p)(const void*)g, (as3_u32p)(void*)l,
                                   16, 0, 0);
}

// ---------------------------------------------------------------------------
// Weight transpose + cast: w[K][N] fp32 -> wt[N][K] bf16
// ---------------------------------------------------------------------------
__global__ __launch_bounds__(256)
void transpose_cast(const float* __restrict__ w, unsigned short* __restrict__ wt,
                    int K, int N) {
  __shared__ float tile[32][33];
  const int k0 = blockIdx.y * 32;
  const int n0 = blockIdx.x * 32;
  const int tx = threadIdx.x & 31;
  const int ty = threadIdx.x >> 5;  // 0..7
#pragma unroll
  for (int i = 0; i < 4; i++)
    tile[ty + i * 8][tx] = w[(size_t)(k0 + ty + i * 8) * N + n0 + tx];
  __syncthreads();
#pragma unroll
  for (int i = 0; i < 4; i++)
    wt[(size_t)(n0 + ty + i * 8) * K + k0 + tx] = f2bf(tile[tx][ty + i * 8]);
}

// ---------------------------------------------------------------------------
// LayerNorm: x[rows][1024] fp32 -> out bf16
// ---------------------------------------------------------------------------
__global__ __launch_bounds__(256)
void ln_kernel(const float* __restrict__ x, const float* __restrict__ g,
               const float* __restrict__ b, unsigned short* __restrict__ out) {
  const int row = blockIdx.x;
  const int tid = threadIdx.x;
  const float4* xr = (const float4*)&x[(size_t)row * DIMC];
  float4 v = xr[tid];
  float s  = v.x + v.y + v.z + v.w;
  float sq = v.x * v.x + v.y * v.y + v.z * v.z + v.w * v.w;
#pragma unroll
  for (int off = 32; off > 0; off >>= 1) {
    s  += __shfl_xor(s, off, 64);
    sq += __shfl_xor(sq, off, 64);
  }
  __shared__ float red[8];
  if ((tid & 63) == 0) { red[tid >> 6] = s; red[4 + (tid >> 6)] = sq; }
  __syncthreads();
  s  = red[0] + red[1] + red[2] + red[3];
  sq = red[4] + red[5] + red[6] + red[7];
  const float mu  = s * (1.0f / DIMC);
  const float var = sq * (1.0f / DIMC) - mu * mu;
  const float rs  = rsqrtf(var + 1e-5f);
  const int c = tid * 4;
  float vv[4] = {v.x, v.y, v.z, v.w};
#pragma unroll
  for (int j = 0; j < 4; j++)
    out[(size_t)row * DIMC + c + j] = f2bf((vv[j] - mu) * rs * g[c + j] + b[c + j]);
}

// ---------------------------------------------------------------------------
// GEMM: C[M][N] = A[M][K] @ B, Bt[N][K] bf16. 128x128 tile, BK=32, 4 waves,
// 4x4 MFMA acc/wave. Staging via global_load_lds width=16 (m97 pattern):
// LDS byte dest == tid*16, i.e. wave-uniform base + lane*16. Tiles unpadded.
// EPI: 0 = bf16 store; 1 = +bias+res fp32; 2 = gelu(+bias) bf16
// ---------------------------------------------------------------------------
template <int EPI>
__global__ __launch_bounds__(256, 2)
void gemm_bt(const unsigned short* __restrict__ A,
             const unsigned short* __restrict__ Bt,
             float* __restrict__ Cf, unsigned short* __restrict__ Cb,
             const float* __restrict__ bias, const float* __restrict__ res,
             int M, int N, int K) {
  __shared__ unsigned short As[128 * 32];
  __shared__ unsigned short Bs[128 * 32];
  const int tid  = threadIdx.x;
  const int lane = tid & 63;
  const int wave = tid >> 6;
  const int m0 = blockIdx.y * 128;
  const int n0 = blockIdx.x * 128;
  const int wm = (wave >> 1) * 64;
  const int wn = (wave & 1) * 64;
  const int lm = lane & 15;
  const int lg = lane >> 4;
  const int arow = tid >> 2;   // 0..63
  const int achk = tid & 3;    // 0..3 -> k-chunk of 8

  const unsigned short* gA0 = &A [(size_t)(m0 + arow)      * K + achk * 8];
  const unsigned short* gA1 = &A [(size_t)(m0 + 64 + arow) * K + achk * 8];
  const unsigned short* gB0 = &Bt[(size_t)(n0 + arow)      * K + achk * 8];
  const unsigned short* gB1 = &Bt[(size_t)(n0 + 64 + arow) * K + achk * 8];
  unsigned short* lA0 = &As[wave * 512];          // bytes: wave*1024 + lane*16
  unsigned short* lA1 = &As[2048 + wave * 512];
  unsigned short* lB0 = &Bs[wave * 512];
  unsigned short* lB1 = &Bs[2048 + wave * 512];

  f32x4 acc[4][4];
#pragma unroll
  for (int t = 0; t < 4; t++)
#pragma unroll
    for (int u = 0; u < 4; u++) acc[t][u] = {0.f, 0.f, 0.f, 0.f};

  for (int k0 = 0; k0 < K; k0 += 32) {
    __syncthreads();                 // prior tile's LDS reads done
    gload_lds16(gA0 + k0, lA0);
    gload_lds16(gA1 + k0, lA1);
    gload_lds16(gB0 + k0, lB0);
    gload_lds16(gB1 + k0, lB1);
    __syncthreads();                 // compiler drains vmcnt before barrier
    bf16x8 af[4], bfr[4];
#pragma unroll
    for (int t = 0; t < 4; t++) af[t]  = *(const bf16x8*)&As[(wm + t * 16 + lm) * 32 + lg * 8];
#pragma unroll
    for (int u = 0; u < 4; u++) bfr[u] = *(const bf16x8*)&Bs[(wn + u * 16 + lm) * 32 + lg * 8];
#pragma unroll
    for (int t = 0; t < 4; t++)
#pragma unroll
      for (int u = 0; u < 4; u++)
        acc[t][u] = mfma_bf16(af[t], bfr[u], acc[t][u]);
  }

#pragma unroll
  for (int t = 0; t < 4; t++) {
    const int row = m0 + wm + t * 16 + lg * 4;
#pragma unroll
    for (int u = 0; u < 4; u++) {
      const int col = n0 + wn + u * 16 + lm;
#pragma unroll
      for (int r = 0; r < 4; r++) {
        float v = acc[t][u][r];
        size_t idx = (size_t)(row + r) * N + col;
        if (EPI == 0) {
          Cb[idx] = f2bf(v);
        } else if (EPI == 1) {
          Cf[idx] = v + bias[col] + res[idx];
        } else {
          float xg = v + bias[col];
          Cb[idx] = f2bf(0.5f * xg * (1.0f + erff(xg * 0.70710678118654752f)));
        }
      }
    }
  }
}

// ---------------------------------------------------------------------------
// Flash attention, transposed scores. qkv[TOK][3072] bf16 (q/k/v at
// +0/+1024/+2048, head h at h*64). Block = (b,h, 64 q-rows); wave = 16 rows.
//   S^T = K@Q^T : A=K (LDS Ks, natural), B=Q (global, natural)
//   softmax: row = lane&15 -> in-lane reduce + shfl_xor(16,32); log2 domain
//   O^T += V^T@P^T : A=V^T (LDS Vt, XOR-swizzled 8-key chunks), B=P^T (LDS Ps)
// ---------------------------------------------------------------------------
__global__ __launch_bounds__(256, 2)
void attn_kernel(const unsigned short* __restrict__ qkv,
                 unsigned short* __restrict__ out) {
  const int qt = blockIdx.x;
  const int bh = blockIdx.y;
  const int b  = bh >> 4;
  const int h  = bh & 15;
  const int tid  = threadIdx.x;
  const int lane = tid & 63;
  const int wave = tid >> 6;
  const int lm = lane & 15;
  const int lg = lane >> 4;

  __shared__ unsigned short Ks[64 * 72];        // [key][d], +8 pad
  __shared__ unsigned short Vt[64 * 64];        // [d][key], chunk c at c^(d&7)
  __shared__ unsigned short Ps[4][16 * 72];     // per-wave P[q][key], +8 pad

  const int qrow_base = b * SEQ + qt * 64 + wave * 16;
  bf16x8 qb[2];  // B-frag: Bt[n=q][k=d] = Q natural
#pragma unroll
  for (int c = 0; c < 2; c++)
    qb[c] = *(const bf16x8*)&qkv[(size_t)(qrow_base + lm) * 3072 + h * 64 + c * 32 + lg * 8];

  f32x4 o[4];   // O^T accum: m = d (4 tiles of 16), n = q = lm
#pragma unroll
  for (int dt = 0; dt < 4; dt++) o[dt] = {0.f, 0.f, 0.f, 0.f};
  float mi = -1e30f, li = 0.f;   // per-lane scalars (row lm), mi in log2 dom
  const float LC = 0.125f * 1.44269504088896f;  // scale * log2(e)

  const int key_l = tid & 63;   // K staging: lane = key
  const int chk_l = tid >> 6;   // d-chunk
  const int vd    = tid & 63;   // V staging: lane = d (coalesced gathers)
  const int vkb   = tid >> 6;   // key-chunk pair vkb, vkb+4
  const int vsw   = vd & 7;     // Vt XOR swizzle

  for (int kt = 0; kt < SEQ / 64; kt++) {
    const int kbase = b * SEQ + kt * 64;
    // K rows: 2 x b128 per thread
    const size_t krow = (size_t)(kbase + key_l) * 3072 + 1024 + h * 64;
    ushort8 kv0 = *(const ushort8*)&qkv[krow + chk_l * 8];
    ushort8 kv1 = *(const ushort8*)&qkv[krow + 32 + chk_l * 8];
    // V columns: gather 2x8 keys for one d (lanes = consecutive d, coalesced)
    const size_t vbase = (size_t)kbase * 3072 + 2048 + h * 64 + vd;
    ushort8 vv0, vv1;
#pragma unroll
    for (int j = 0; j < 8; j++) {
      vv0[j] = qkv[vbase + (size_t)(vkb * 8 + j) * 3072];
      vv1[j] = qkv[vbase + (size_t)(vkb * 8 + 32 + j) * 3072];
    }
    __syncthreads();
    *(ushort8*)&Ks[key_l * 72 + chk_l * 8]      = kv0;
    *(ushort8*)&Ks[key_l * 72 + 32 + chk_l * 8] = kv1;
    *(ushort8*)&Vt[vd * 64 + (vkb ^ vsw) * 8]       = vv0;
    *(ushort8*)&Vt[vd * 64 + ((vkb + 4) ^ vsw) * 8] = vv1;
    __syncthreads();

    // S^T[key][q]: 4 m-tiles of 16 keys
    f32x4 st[4];
#pragma unroll
    for (int u = 0; u < 4; u++) {
      bf16x8 ka0 = *(const bf16x8*)&Ks[(u * 16 + lm) * 72 + lg * 8];
      bf16x8 ka1 = *(const bf16x8*)&Ks[(u * 16 + lm) * 72 + 32 + lg * 8];
      f32x4 z = {0.f, 0.f, 0.f, 0.f};
      z = mfma_bf16(ka0, qb[0], z);
      z = mfma_bf16(ka1, qb[1], z);
      st[u] = z;
    }

    // online softmax, row = lm, all 16 in-lane values belong to that row
    float mx = -1e30f;
#pragma unroll
    for (int u = 0; u < 4; u++)
#pragma unroll
      for (int r = 0; r < 4; r++) mx = fmaxf(mx, st[u][r]);
    mx = fmaxf(mx, __shfl_xor(mx, 16, 64));
    mx = fmaxf(mx, __shfl_xor(mx, 32, 64));
    const float mnew = fmaxf(mi, mx * LC);
    const float alpha = exp2f(mi - mnew);
    float ps = 0.f;
#pragma unroll
    for (int u = 0; u < 4; u++)
#pragma unroll
      for (int r = 0; r < 4; r++) {
        float p = exp2f(fmaf(st[u][r], LC, -mnew));
        st[u][r] = p;
        ps += p;
      }
    ps += __shfl_xor(ps, 16, 64);
    ps += __shfl_xor(ps, 32, 64);
    li = li * alpha + ps;
    mi = mnew;
#pragma unroll
    for (int dt = 0; dt < 4; dt++) o[dt] *= alpha;

    // P^T (C-layout) -> Ps[q=lm][key], 4 x b64 packed writes per lane
#pragma unroll
    for (int u = 0; u < 4; u++) {
      ushort4v pk = {f2bf(st[u][0]), f2bf(st[u][1]), f2bf(st[u][2]), f2bf(st[u][3])};
      *(ushort4v*)&Ps[wave][lm * 72 + u * 16 + lg * 4] = pk;
    }

    // O^T += V^T @ P^T
#pragma unroll
    for (int kc = 0; kc < 2; kc++) {
      bf16x8 pb = *(const bf16x8*)&Ps[wave][lm * 72 + kc * 32 + lg * 8];
#pragma unroll
      for (int dt = 0; dt < 4; dt++) {
        bf16x8 va = *(const bf16x8*)&Vt[(dt * 16 + lm) * 64 + ((kc * 4 + lg) ^ (lm & 7)) * 8];
        o[dt] = mfma_bf16(va, pb, o[dt]);
      }
    }
  }

  const float inv = 1.0f / li;
#pragma unroll
  for (int dt = 0; dt < 4; dt++) {
    ushort4v ok = {f2bf(o[dt][0] * inv), f2bf(o[dt][1] * inv),
                   f2bf(o[dt][2] * inv), f2bf(o[dt][3] * inv)};
    *(ushort4v*)&out[(size_t)(qrow_base + lm) * DIMC + h * 64 + dt * 16 + lg * 4] = ok;
  }
}

// ---------------------------------------------------------------------------
extern "C" void kernel_launch(void* const* d_in, const int* in_sizes, int n_in,
                              void* d_out, int out_size, void* d_ws, size_t ws_size,
                              hipStream_t stream) {
  const float* x      = (const float*)d_in[0];
  const float* ln1_g  = (const float*)d_in[1];
  const float* ln1_b  = (const float*)d_in[2];
  const float* w_qkv  = (const float*)d_in[3];
  const float* w_proj = (const float*)d_in[4];
  const float* b_proj = (const float*)d_in[5];
  const float* ln2_g  = (const float*)d_in[6];
  const float* ln2_b  = (const float*)d_in[7];
  const float* w1     = (const float*)d_in[8];
  const float* b1     = (const float*)d_in[9];
  const float* w2     = (const float*)d_in[10];
  const float* b2     = (const float*)d_in[11];
  float* out = (float*)d_out;

  char* ws = (char*)d_ws;
  size_t off = 0;
  auto alloc = [&](size_t bytes) { void* p = ws + off; off += (bytes + 255) & ~(size_t)255; return p; };
  unsigned short* wqkvT = (unsigned short*)alloc((size_t)3072 * 1024 * 2);
  unsigned short* wprjT = (unsigned short*)alloc((size_t)1024 * 1024 * 2);
  unsigned short* w1T   = (unsigned short*)alloc((size_t)4096 * 1024 * 2);
  unsigned short* w2T   = (unsigned short*)alloc((size_t)1024 * 4096 * 2);
  unsigned short* hb    = (unsigned short*)alloc((size_t)TOK * 1024 * 2);
  unsigned short* qkvb  = (unsigned short*)alloc((size_t)TOK * 3072 * 2);
  unsigned short* attnb = (unsigned short*)alloc((size_t)TOK * 1024 * 2);
  float*          x1    = (float*)         alloc((size_t)TOK * 1024 * 4);
  unsigned short* hidb  = (unsigned short*)alloc((size_t)TOK * 4096 * 2);

  transpose_cast<<<dim3(3072 / 32, 1024 / 32), 256, 0, stream>>>(w_qkv, wqkvT, 1024, 3072);
  transpose_cast<<<dim3(1024 / 32, 1024 / 32), 256, 0, stream>>>(w_proj, wprjT, 1024, 1024);
  transpose_cast<<<dim3(4096 / 32, 1024 / 32), 256, 0, stream>>>(w1, w1T, 1024, 4096);
  transpose_cast<<<dim3(1024 / 32, 4096 / 32), 256, 0, stream>>>(w2, w2T, 4096, 1024);
  ln_kernel<<<TOK, 256, 0, stream>>>(x, ln1_g, ln1_b, hb);
  gemm_bt<0><<<dim3(3072 / 128, TOK / 128), 256, 0, stream>>>(
      hb, wqkvT, nullptr, qkvb, nullptr, nullptr, TOK, 3072, 1024);
  attn_kernel<<<dim3(SEQ / 64, 32), 256, 0, stream>>>(qkvb, attnb);
  gemm_bt<1><<<dim3(1024 / 128, TOK / 128), 256, 0, stream>>>(
      attnb, wprjT, x1, nullptr, b_proj, x, TOK, 1024, 1024);
  ln_kernel<<<TOK, 256, 0, stream>>>(x1, ln2_g, ln2_b, hb);
  gemm_bt<2><<<dim3(4096 / 128, TOK / 128), 256, 0, stream>>>(
      hb, w1T, nullptr, hidb, b1, nullptr, TOK, 4096, 1024);
  gemm_bt<1><<<dim3(1024 / 128, TOK / 128), 256, 0, stream>>>(
      hidb, w2T, out, nullptr, b2, x1, TOK, 1024, 4096);
}

// Round 3
// 396.432 us; speedup vs baseline: 1.1467x; 1.0732x over previous
//
#include <hip/hip_runtime.h>
#include <stdint.h>

// ---------------------------------------------------------------------------
// Transformer block: LN1 -> QKV GEMM -> repack K/V -> flash-MFMA attention
//                    -> proj(+res) -> LN2 -> MLP1(GELU) -> MLP2(+res)
// All matmuls: bf16 inputs, fp32 MFMA accumulation (16x16x32_bf16).
// Fragment layouts (learn_hip m89/m91):
//   A-frag:  A[m = lane&15][k = (lane>>4)*8 + j]   (8 bf16, contiguous in k)
//   B-frag:  B[k = (lane>>4)*8 + j][n = lane&15]   (= Bt[n][k], contiguous k)
//   C/D   :  D[m = (lane>>4)*4 + r][n = lane&15]
// Attention: S^T = K@Q^T so softmax rows live per-lane (q = lane&15);
// K/V pre-packed per-head (kT[bh][key][d], vT[bh][d][key]) so all attn
// staging is coalesced b128.
// ---------------------------------------------------------------------------

#define DIMC 1024
#define HIDN 4096
#define SEQ  2048
#define TOK  4096   // B*N = 2*2048

typedef __bf16 bf16x8 __attribute__((ext_vector_type(8)));
typedef float  f32x4  __attribute__((ext_vector_type(4)));
typedef unsigned short ushort8 __attribute__((ext_vector_type(8)));

__device__ inline unsigned short f2bf(float f) {
  union { float f; unsigned u; } v; v.f = f;
  unsigned u = v.u;
  return (unsigned short)((u + 0x7fffu + ((u >> 16) & 1u)) >> 16);  // RNE
}

// HW packed fp32->bf16 (CDNA3+): lo = cvt(a), hi = cvt(b)
__device__ inline unsigned cvt_pk_bf16(float a, float b) {
  unsigned r;
  asm("v_cvt_pk_bf16_f32 %0, %1, %2" : "=v"(r) : "v"(a), "v"(b));
  return r;
}

__device__ inline f32x4 mfma_bf16(bf16x8 a, bf16x8 b, f32x4 c) {
  return __builtin_amdgcn_mfma_f32_16x16x32_bf16(a, b, c, 0, 0, 0);
}

// async global->LDS, 16B per lane; LDS dest = wave-uniform base + lane*16
typedef const __attribute__((address_space(1))) unsigned int* as1_u32p;
typedef __attribute__((address_space(3))) unsigned int* as3_u32p;
__device__ inline void gload_lds16(const unsigned short* g, unsigned short* l) {
  __builtin_amdgcn_global_load_lds((as1_u32p)(const void*)g, (as3_u32p)(void*)l,
                                   16, 0, 0);
}

// ---------------------------------------------------------------------------
// Weight transpose + cast: w[K][N] fp32 -> wt[N][K] bf16
// ---------------------------------------------------------------------------
__global__ __launch_bounds__(256)
void transpose_cast(const float* __restrict__ w, unsigned short* __restrict__ wt,
                    int K, int N) {
  __shared__ float tile[32][33];
  const int k0 = blockIdx.y * 32;
  const int n0 = blockIdx.x * 32;
  const int tx = threadIdx.x & 31;
  const int ty = threadIdx.x >> 5;  // 0..7
#pragma unroll
  for (int i = 0; i < 4; i++)
    tile[ty + i * 8][tx] = w[(size_t)(k0 + ty + i * 8) * N + n0 + tx];
  __syncthreads();
#pragma unroll
  for (int i = 0; i < 4; i++)
    wt[(size_t)(n0 + ty + i * 8) * K + k0 + tx] = f2bf(tile[tx][ty + i * 8]);
}

// ---------------------------------------------------------------------------
// LayerNorm: x[rows][1024] fp32 -> out bf16
// ---------------------------------------------------------------------------
__global__ __launch_bounds__(256)
void ln_kernel(const float* __restrict__ x, const float* __restrict__ g,
               const float* __restrict__ b, unsigned short* __restrict__ out) {
  const int row = blockIdx.x;
  const int tid = threadIdx.x;
  const float4* xr = (const float4*)&x[(size_t)row * DIMC];
  float4 v = xr[tid];
  float s  = v.x + v.y + v.z + v.w;
  float sq = v.x * v.x + v.y * v.y + v.z * v.z + v.w * v.w;
#pragma unroll
  for (int off = 32; off > 0; off >>= 1) {
    s  += __shfl_xor(s, off, 64);
    sq += __shfl_xor(sq, off, 64);
  }
  __shared__ float red[8];
  if ((tid & 63) == 0) { red[tid >> 6] = s; red[4 + (tid >> 6)] = sq; }
  __syncthreads();
  s  = red[0] + red[1] + red[2] + red[3];
  sq = red[4] + red[5] + red[6] + red[7];
  const float mu  = s * (1.0f / DIMC);
  const float var = sq * (1.0f / DIMC) - mu * mu;
  const float rs  = rsqrtf(var + 1e-5f);
  const int c = tid * 4;
  float vv[4] = {v.x, v.y, v.z, v.w};
#pragma unroll
  for (int j = 0; j < 4; j++)
    out[(size_t)row * DIMC + c + j] = f2bf((vv[j] - mu) * rs * g[c + j] + b[c + j]);
}

// ---------------------------------------------------------------------------
// GEMM: C[M][N] = A[M][K] @ B, Bt[N][K] bf16. 128xTN tile, BK=32, 4 waves.
// TN=128: waves 2x2 of 64x64 (4x4 acc);  TN=64: waves 2x2 of 64x32 (4x2 acc,
// more blocks for narrow-N shapes). Staging via global_load_lds width=16.
// EPI: 0 = bf16 store; 1 = +bias+res fp32; 2 = gelu(+bias) bf16
// ---------------------------------------------------------------------------
template <int EPI, int TN>
__global__ __launch_bounds__(256, (TN == 64) ? 4 : 2)
void gemm_bt(const unsigned short* __restrict__ A,
             const unsigned short* __restrict__ Bt,
             float* __restrict__ Cf, unsigned short* __restrict__ Cb,
             const float* __restrict__ bias, const float* __restrict__ res,
             int M, int N, int K) {
  constexpr int NU = TN / 32;            // B n-tiles per wave
  __shared__ unsigned short As[128 * 32];
  __shared__ unsigned short Bs[TN * 32];
  const int tid  = threadIdx.x;
  const int lane = tid & 63;
  const int wave = tid >> 6;
  const int m0 = blockIdx.y * 128;
  const int n0 = blockIdx.x * TN;
  const int wm = (wave >> 1) * 64;
  const int wn = (wave & 1) * (TN / 2);
  const int lm = lane & 15;
  const int lg = lane >> 4;
  const int arow = tid >> 2;   // 0..63
  const int achk = tid & 3;    // 0..3 -> k-chunk of 8

  const unsigned short* gA0 = &A [(size_t)(m0 + arow)      * K + achk * 8];
  const unsigned short* gA1 = &A [(size_t)(m0 + 64 + arow) * K + achk * 8];
  const unsigned short* gB0 = &Bt[(size_t)(n0 + arow)      * K + achk * 8];
  const unsigned short* gB1 = (TN == 128) ? &Bt[(size_t)(n0 + 64 + arow) * K + achk * 8] : nullptr;
  unsigned short* lA0 = &As[wave * 512];          // bytes: wave*1024 + lane*16
  unsigned short* lA1 = &As[2048 + wave * 512];
  unsigned short* lB0 = &Bs[wave * 512];
  unsigned short* lB1 = (TN == 128) ? &Bs[2048 + wave * 512] : nullptr;

  f32x4 acc[4][NU];
#pragma unroll
  for (int t = 0; t < 4; t++)
#pragma unroll
    for (int u = 0; u < NU; u++) acc[t][u] = {0.f, 0.f, 0.f, 0.f};

  for (int k0 = 0; k0 < K; k0 += 32) {
    __syncthreads();                 // prior tile's LDS reads done
    gload_lds16(gA0 + k0, lA0);
    gload_lds16(gA1 + k0, lA1);
    gload_lds16(gB0 + k0, lB0);
    if (TN == 128) gload_lds16(gB1 + k0, lB1);
    __syncthreads();                 // compiler drains vmcnt before barrier
    bf16x8 af[4], bfr[NU];
#pragma unroll
    for (int t = 0; t < 4; t++)  af[t]  = *(const bf16x8*)&As[(wm + t * 16 + lm) * 32 + lg * 8];
#pragma unroll
    for (int u = 0; u < NU; u++) bfr[u] = *(const bf16x8*)&Bs[(wn + u * 16 + lm) * 32 + lg * 8];
#pragma unroll
    for (int t = 0; t < 4; t++)
#pragma unroll
      for (int u = 0; u < NU; u++)
        acc[t][u] = mfma_bf16(af[t], bfr[u], acc[t][u]);
  }

#pragma unroll
  for (int t = 0; t < 4; t++) {
    const int row = m0 + wm + t * 16 + lg * 4;
#pragma unroll
    for (int u = 0; u < NU; u++) {
      const int col = n0 + wn + u * 16 + lm;
#pragma unroll
      for (int r = 0; r < 4; r++) {
        float v = acc[t][u][r];
        size_t idx = (size_t)(row + r) * N + col;
        if (EPI == 0) {
          Cb[idx] = f2bf(v);
        } else if (EPI == 1) {
          Cf[idx] = v + bias[col] + res[idx];
        } else {
          float xg = v + bias[col];
          Cb[idx] = f2bf(0.5f * xg * (1.0f + erff(xg * 0.70710678118654752f)));
        }
      }
    }
  }
}

// ---------------------------------------------------------------------------
// Repack K,V per head: kT[bh][key][d] (head-gather), vT[bh][d][key]
// (transpose via LDS). qkv[token][3072], K at +1024, V at +2048, head h*64.
// grid (SEQ/64, 32 bh), 256 threads. All global loads/stores b128-coalesced.
// ---------------------------------------------------------------------------
__global__ __launch_bounds__(256)
void repack_kv(const unsigned short* __restrict__ qkv,
               unsigned short* __restrict__ kT, unsigned short* __restrict__ vT) {
  const int kt = blockIdx.x;
  const int bh = blockIdx.y;
  const int b = bh >> 4, h = bh & 15;
  const int tid = threadIdx.x;
  __shared__ unsigned short tile[64 * 72];
  const int tok = tid >> 2;       // 0..63
  const int ch  = tid & 3;        // chunks ch, ch+4 (8 d each)
  const size_t srow = (size_t)(b * SEQ + kt * 64 + tok) * 3072 + h * 64;
  // K: straight copy
  ushort8 ka = *(const ushort8*)&qkv[srow + 1024 + ch * 8];
  ushort8 kb = *(const ushort8*)&qkv[srow + 1024 + 32 + ch * 8];
  const size_t kdst = ((size_t)bh * SEQ + kt * 64 + tok) * 64;
  *(ushort8*)&kT[kdst + ch * 8] = ka;
  *(ushort8*)&kT[kdst + 32 + ch * 8] = kb;
  // V: transpose via LDS
  ushort8 va = *(const ushort8*)&qkv[srow + 2048 + ch * 8];
  ushort8 vb = *(const ushort8*)&qkv[srow + 2048 + 32 + ch * 8];
  *(ushort8*)&tile[tok * 72 + ch * 8] = va;
  *(ushort8*)&tile[tok * 72 + 32 + ch * 8] = vb;
  __syncthreads();
  const int d = tid >> 2;         // 0..63
  ushort8 o0, o1;
#pragma unroll
  for (int j = 0; j < 8; j++) {
    o0[j] = tile[(ch * 8 + j) * 72 + d];
    o1[j] = tile[((ch + 4) * 8 + j) * 72 + d];
  }
  const size_t vdst = ((size_t)bh * 64 + d) * SEQ + kt * 64;
  *(ushort8*)&vT[vdst + ch * 8] = o0;
  *(ushort8*)&vT[vdst + 32 + ch * 8] = o1;
}

// ---------------------------------------------------------------------------
// Flash attention, transposed scores. Block = (qt: 64 q-rows, bh); wave = 16
// q-rows. S^T = K@Q^T (A=Ks natural, B=Q global); softmax per-lane (q=lm),
// log2 domain; O^T += V^T@P^T (A=Vs from vT, B=Ps). All staging b128.
// ---------------------------------------------------------------------------
__global__ __launch_bounds__(256, 2)
void attn_kernel(const unsigned short* __restrict__ qkv,
                 const unsigned short* __restrict__ kT,
                 const unsigned short* __restrict__ vT,
                 unsigned short* __restrict__ out) {
  const int qt = blockIdx.x;
  const int bh = blockIdx.y;
  const int b  = bh >> 4;
  const int h  = bh & 15;
  const int tid  = threadIdx.x;
  const int lane = tid & 63;
  const int wave = tid >> 6;
  const int lm = lane & 15;
  const int lg = lane >> 4;

  __shared__ unsigned short Ks[64 * 72];        // [key][d], +8 pad
  __shared__ unsigned short Vs[64 * 72];        // [d][key], +8 pad
  __shared__ unsigned short Ps[4][16 * 72];     // per-wave P^T[q][key], +8 pad

  const int qrow_base = b * SEQ + qt * 64 + wave * 16;
  bf16x8 qb[2];  // B-frag: Bt[n=q][k=d] = Q natural
#pragma unroll
  for (int c = 0; c < 2; c++)
    qb[c] = *(const bf16x8*)&qkv[(size_t)(qrow_base + lm) * 3072 + h * 64 + c * 32 + lg * 8];

  f32x4 o[4];   // O^T accum: m = d (4 tiles of 16), n = q = lm
#pragma unroll
  for (int dt = 0; dt < 4; dt++) o[dt] = {0.f, 0.f, 0.f, 0.f};
  float mi = -1e30f, li = 0.f;   // per-lane scalars (row lm), log2 domain
  const float LC = 0.125f * 1.44269504088896f;  // scale * log2(e)

  const unsigned short* kbp = &kT[(size_t)bh * SEQ * 64];
  const unsigned short* vbp = &vT[(size_t)bh * 64 * SEQ];
  const int srow = tid >> 3;       // 0..31 (row within tile half)
  const int sch  = tid & 7;        // 16B chunk within 128B row

  for (int kt = 0; kt < SEQ / 64; kt++) {
    // K tile: 8KB contiguous; V tile: 64 rows of 128B (row stride SEQ*2B)
    ushort8 kv0 = *(const ushort8*)&kbp[(size_t)kt * 4096 + tid * 8];
    ushort8 kv1 = *(const ushort8*)&kbp[(size_t)kt * 4096 + 2048 + tid * 8];
    ushort8 vv0 = *(const ushort8*)&vbp[(size_t)srow * SEQ + kt * 64 + sch * 8];
    ushort8 vv1 = *(const ushort8*)&vbp[(size_t)(srow + 32) * SEQ + kt * 64 + sch * 8];
    __syncthreads();
    *(ushort8*)&Ks[srow * 72 + sch * 8]        = kv0;
    *(ushort8*)&Ks[(srow + 32) * 72 + sch * 8] = kv1;
    *(ushort8*)&Vs[srow * 72 + sch * 8]        = vv0;
    *(ushort8*)&Vs[(srow + 32) * 72 + sch * 8] = vv1;
    __syncthreads();

    // S^T[key][q]: 4 m-tiles of 16 keys
    f32x4 st[4];
#pragma unroll
    for (int u = 0; u < 4; u++) {
      bf16x8 ka0 = *(const bf16x8*)&Ks[(u * 16 + lm) * 72 + lg * 8];
      bf16x8 ka1 = *(const bf16x8*)&Ks[(u * 16 + lm) * 72 + 32 + lg * 8];
      f32x4 z = {0.f, 0.f, 0.f, 0.f};
      z = mfma_bf16(ka0, qb[0], z);
      z = mfma_bf16(ka1, qb[1], z);
      st[u] = z;
    }

    // online softmax, row = lm; in-lane reduce + shfl_xor(16,32)
    float mx = -1e30f;
#pragma unroll
    for (int u = 0; u < 4; u++)
#pragma unroll
      for (int r = 0; r < 4; r++) mx = fmaxf(mx, st[u][r]);
    mx = fmaxf(mx, __shfl_xor(mx, 16, 64));
    mx = fmaxf(mx, __shfl_xor(mx, 32, 64));
    const float mnew = fmaxf(mi, mx * LC);
    const float alpha = exp2f(mi - mnew);
    float ps = 0.f;
#pragma unroll
    for (int u = 0; u < 4; u++)
#pragma unroll
      for (int r = 0; r < 4; r++) {
        float p = exp2f(fmaf(st[u][r], LC, -mnew));
        st[u][r] = p;
        ps += p;
      }
    ps += __shfl_xor(ps, 16, 64);
    ps += __shfl_xor(ps, 32, 64);
    li = li * alpha + ps;
    mi = mnew;
#pragma unroll
    for (int dt = 0; dt < 4; dt++) o[dt] *= alpha;

    // P^T (C-layout) -> Ps[q=lm][key], HW packed cvt + b64 writes
#pragma unroll
    for (int u = 0; u < 4; u++) {
      uint2 pk;
      pk.x = cvt_pk_bf16(st[u][0], st[u][1]);
      pk.y = cvt_pk_bf16(st[u][2], st[u][3]);
      *(uint2*)&Ps[wave][lm * 72 + u * 16 + lg * 4] = pk;
    }

    // O^T += V^T @ P^T
#pragma unroll
    for (int kc = 0; kc < 2; kc++) {
      bf16x8 pb = *(const bf16x8*)&Ps[wave][lm * 72 + kc * 32 + lg * 8];
#pragma unroll
      for (int dt = 0; dt < 4; dt++) {
        bf16x8 va = *(const bf16x8*)&Vs[(dt * 16 + lm) * 72 + kc * 32 + lg * 8];
        o[dt] = mfma_bf16(va, pb, o[dt]);
      }
    }
  }

  const float inv = 1.0f / li;
#pragma unroll
  for (int dt = 0; dt < 4; dt++) {
    uint2 ok;
    ok.x = cvt_pk_bf16(o[dt][0] * inv, o[dt][1] * inv);
    ok.y = cvt_pk_bf16(o[dt][2] * inv, o[dt][3] * inv);
    *(uint2*)&out[(size_t)(qrow_base + lm) * DIMC + h * 64 + dt * 16 + lg * 4] = ok;
  }
}

// ---------------------------------------------------------------------------
extern "C" void kernel_launch(void* const* d_in, const int* in_sizes, int n_in,
                              void* d_out, int out_size, void* d_ws, size_t ws_size,
                              hipStream_t stream) {
  const float* x      = (const float*)d_in[0];
  const float* ln1_g  = (const float*)d_in[1];
  const float* ln1_b  = (const float*)d_in[2];
  const float* w_qkv  = (const float*)d_in[3];
  const float* w_proj = (const float*)d_in[4];
  const float* b_proj = (const float*)d_in[5];
  const float* ln2_g  = (const float*)d_in[6];
  const float* ln2_b  = (const float*)d_in[7];
  const float* w1     = (const float*)d_in[8];
  const float* b1     = (const float*)d_in[9];
  const float* w2     = (const float*)d_in[10];
  const float* b2     = (const float*)d_in[11];
  float* out = (float*)d_out;

  char* ws = (char*)d_ws;
  size_t off = 0;
  auto alloc = [&](size_t bytes) { void* p = ws + off; off += (bytes + 255) & ~(size_t)255; return p; };
  unsigned short* wqkvT = (unsigned short*)alloc((size_t)3072 * 1024 * 2);
  unsigned short* wprjT = (unsigned short*)alloc((size_t)1024 * 1024 * 2);
  unsigned short* w1T   = (unsigned short*)alloc((size_t)4096 * 1024 * 2);
  unsigned short* w2T   = (unsigned short*)alloc((size_t)1024 * 4096 * 2);
  unsigned short* hb    = (unsigned short*)alloc((size_t)TOK * 1024 * 2);
  unsigned short* qkvb  = (unsigned short*)alloc((size_t)TOK * 3072 * 2);
  unsigned short* attnb = (unsigned short*)alloc((size_t)TOK * 1024 * 2);
  float*          x1    = (float*)         alloc((size_t)TOK * 1024 * 4);
  unsigned short* hidb  = (unsigned short*)alloc((size_t)TOK * 4096 * 2);
  // kT/vT overlay hidb (32MB >= 16MB): attn finishes before MLP1 writes hidb
  unsigned short* kT = hidb;                              // 8 MB
  unsigned short* vT = hidb + (size_t)32 * SEQ * 64;      // 8 MB

  transpose_cast<<<dim3(3072 / 32, 1024 / 32), 256, 0, stream>>>(w_qkv, wqkvT, 1024, 3072);
  transpose_cast<<<dim3(1024 / 32, 1024 / 32), 256, 0, stream>>>(w_proj, wprjT, 1024, 1024);
  transpose_cast<<<dim3(4096 / 32, 1024 / 32), 256, 0, stream>>>(w1, w1T, 1024, 4096);
  transpose_cast<<<dim3(1024 / 32, 4096 / 32), 256, 0, stream>>>(w2, w2T, 4096, 1024);
  ln_kernel<<<TOK, 256, 0, stream>>>(x, ln1_g, ln1_b, hb);
  gemm_bt<0, 128><<<dim3(3072 / 128, TOK / 128), 256, 0, stream>>>(
      hb, wqkvT, nullptr, qkvb, nullptr, nullptr, TOK, 3072, 1024);
  repack_kv<<<dim3(SEQ / 64, 32), 256, 0, stream>>>(qkvb, kT, vT);
  attn_kernel<<<dim3(SEQ / 64, 32), 256, 0, stream>>>(qkvb, kT, vT, attnb);
  gemm_bt<1, 64><<<dim3(1024 / 64, TOK / 128), 256, 0, stream>>>(
      attnb, wprjT, x1, nullptr, b_proj, x, TOK, 1024, 1024);
  ln_kernel<<<TOK, 256, 0, stream>>>(x1, ln2_g, ln2_b, hb);
  gemm_bt<2, 128><<<dim3(4096 / 128, TOK / 128), 256, 0, stream>>>(
      hb, w1T, nullptr, hidb, b1, nullptr, TOK, 4096, 1024);
  gemm_bt<1, 64><<<dim3(1024 / 64, TOK / 128), 256, 0, stream>>>(
      hidb, w2T, out, nullptr, b2, x1, TOK, 1024, 4096);
}